// Round 4
// baseline (471.410 us; speedup 1.0000x reference)
//
#include <hip/hip_runtime.h>

#define EMB 128
#define NC 8   // histogram copies (≈ one per XCD)

typedef __attribute__((ext_vector_type(8))) short bf16x8;
typedef __attribute__((ext_vector_type(4))) float f32x4;

__device__ inline unsigned short f2bf(float f) {
  unsigned u = __float_as_uint(f);
  return (unsigned short)((u + 0x7FFF + ((u >> 16) & 1)) >> 16);   // RNE
}
__device__ inline float bf2f(unsigned short s) {
  return __uint_as_float(((unsigned)s) << 16);
}

// ---------- CSR build: privatized histograms (8 copies, ~per-XCD) ----------
__global__ __launch_bounds__(256) void k_count(const int* __restrict__ row,
    const int* __restrict__ col, int* __restrict__ degi8,
    int* __restrict__ cnt8, int* __restrict__ ord, int E, int N) {
  int k = blockIdx.x * 256 + threadIdx.x;
  int copy = blockIdx.x & (NC - 1);
  if (k < E) {
    atomicAdd(&degi8[copy * N + row[k]], 1);          // out-degree (GCN norm)
    ord[k] = atomicAdd(&cnt8[copy * N + col[k]], 1);  // in-degree + order-in-copy
  }
}

// deg[i] = sum over copies; dinv = rsqrt(max(deg,1))
__global__ __launch_bounds__(256) void k_dinv(const int* __restrict__ degi8,
                                              float* __restrict__ dinv, int N) {
  int i = blockIdx.x * 256 + threadIdx.x;
  if (i < N) {
    int d = 0;
#pragma unroll
    for (int c = 0; c < NC; ++c) d += degi8[c * N + i];
    float df = (float)(d == 0 ? 1 : d);
    dinv[i] = 1.0f / sqrtf(df);
  }
}

// in-place exclusive prefix over the 8 copies per node; cnt[i] = total
__global__ __launch_bounds__(256) void k_colreduce(int* __restrict__ cnt8,
                                                   int* __restrict__ cnt, int N) {
  int i = blockIdx.x * 256 + threadIdx.x;
  if (i < N) {
    int s = 0;
#pragma unroll
    for (int c = 0; c < NC; ++c) {
      int v = cnt8[c * N + i];
      cnt8[c * N + i] = s;
      s += v;
    }
    cnt[i] = s;
  }
}

// ---------- multi-block exclusive scan ----------
__global__ __launch_bounds__(256) void k_scan_local(const int* __restrict__ cnt,
    int* __restrict__ startp, int* __restrict__ partial, int N) {
  __shared__ int lds[256];
  int tid = threadIdx.x;
  int i = blockIdx.x * 256 + tid;
  int v = (i < N) ? cnt[i] : 0;
  lds[tid] = v;
  __syncthreads();
#pragma unroll
  for (int off = 1; off < 256; off <<= 1) {
    int t = (tid >= off) ? lds[tid - off] : 0;
    __syncthreads();
    lds[tid] += t;
    __syncthreads();
  }
  if (i < N) startp[i] = lds[tid] - v;
  if (tid == 255) partial[blockIdx.x] = lds[255];
}

__global__ void k_scan_part(int* __restrict__ partial, int nb) {
  __shared__ int lds[1024];
  int tid = threadIdx.x;
  int v = (tid < nb) ? partial[tid] : 0;
  lds[tid] = v;
  __syncthreads();
  for (int off = 1; off < 1024; off <<= 1) {
    int t = (tid >= off) ? lds[tid - off] : 0;
    __syncthreads();
    lds[tid] += t;
    __syncthreads();
  }
  if (tid < nb) partial[tid] = lds[tid] - v;
}

__global__ __launch_bounds__(256) void k_scan_add(int* __restrict__ startp,
    const int* __restrict__ partial, int N, int E) {
  int i = blockIdx.x * 256 + threadIdx.x;
  if (i < N) startp[i] += partial[blockIdx.x];
  if (i == 0) startp[N] = E;
}

__global__ __launch_bounds__(256) void k_fill(const int* __restrict__ row,
    const int* __restrict__ col, const int* __restrict__ attr,
    const int* __restrict__ startp, const int* __restrict__ cnt8,
    const int* __restrict__ ord, const float* __restrict__ dinv,
    int2* __restrict__ emeta, int E, int N) {
  int k = blockIdx.x * 256 + threadIdx.x;
  if (k < E) {
    int r = row[k], c = col[k];
    int copy = (k >> 8) & (NC - 1);            // same map as k_count
    int pos = startp[c] + cnt8[copy * N + c] + ord[k];
    int2 m;
    m.x = r | (attr[k] << 20);
    m.y = __float_as_int(dinv[r] * dinv[c]);
    emeta[pos] = m;
  }
}

// ---------- h0 = atom_emb[x] ----------
__global__ __launch_bounds__(256) void k_h0(const int* __restrict__ x,
    const float* __restrict__ atom_emb, float* __restrict__ h, int N) {
  int t = blockIdx.x * 256 + threadIdx.x;
  int i = t >> 5, f = t & 31;
  if (i < N) {
    float4 v = reinterpret_cast<const float4*>(atom_emb)[x[i] * 32 + f];
    reinterpret_cast<float4*>(h)[i * 32 + f] = v;
  }
}

// ---------- W split: Wt[l][ 0..127 ][k]=hi, Wt[l][128..255][k]=lo (col-major) ----
__global__ __launch_bounds__(256) void k_wsplit(const float* __restrict__ W,
    unsigned short* __restrict__ Wt, int total) {
  int t = blockIdx.x * 256 + threadIdx.x;   // t = (l*128 + k)*128 + n
  if (t >= total) return;
  int n = t & 127, k = (t >> 7) & 127, l = t >> 14;
  float v = W[t];
  unsigned short hi = f2bf(v);
  unsigned short lo = f2bf(v - bf2f(hi));
  size_t base = (size_t)l * 256 * EMB;
  Wt[base + (size_t)n * EMB + k] = hi;
  Wt[base + (size_t)(128 + n) * EMB + k] = lo;
}

// ---------- aggregation: one wave per node; writes split-bf16 agg ----------
__global__ __launch_bounds__(256) void k_agg(const float* __restrict__ h,
    const int* __restrict__ startp, const int2* __restrict__ emeta,
    const float* __restrict__ bond_emb, unsigned short* __restrict__ Ahi,
    unsigned short* __restrict__ Alo, int N, int BV) {
  __shared__ float eb_lds[16 * EMB];
  if (BV <= 16) {
    for (int t = threadIdx.x; t < BV * (EMB / 4); t += 256)
      reinterpret_cast<float4*>(eb_lds)[t] =
          reinterpret_cast<const float4*>(bond_emb)[t];
  }
  __syncthreads();

  int wave = threadIdx.x >> 6, lane = threadIdx.x & 63;
  int node = blockIdx.x * 4 + wave;
  if (node >= N) return;
  int s = startp[node], e = startp[node + 1];
  float accx = 0.f, accy = 0.f;
  int p = s;
  for (; p + 4 <= e; p += 4) {
    int2 m0 = emeta[p + 0];
    int2 m1 = emeta[p + 1];
    int2 m2 = emeta[p + 2];
    int2 m3 = emeta[p + 3];
    float2 a0 = *(reinterpret_cast<const float2*>(h + (size_t)(m0.x & 0xFFFFF) * EMB) + lane);
    float2 a1 = *(reinterpret_cast<const float2*>(h + (size_t)(m1.x & 0xFFFFF) * EMB) + lane);
    float2 a2 = *(reinterpret_cast<const float2*>(h + (size_t)(m2.x & 0xFFFFF) * EMB) + lane);
    float2 a3 = *(reinterpret_cast<const float2*>(h + (size_t)(m3.x & 0xFFFFF) * EMB) + lane);
    float2 e0 = *(reinterpret_cast<const float2*>(eb_lds + (m0.x >> 20) * EMB) + lane);
    float2 e1 = *(reinterpret_cast<const float2*>(eb_lds + (m1.x >> 20) * EMB) + lane);
    float2 e2 = *(reinterpret_cast<const float2*>(eb_lds + (m2.x >> 20) * EMB) + lane);
    float2 e3 = *(reinterpret_cast<const float2*>(eb_lds + (m3.x >> 20) * EMB) + lane);
    float w0 = __int_as_float(m0.y), w1 = __int_as_float(m1.y);
    float w2 = __int_as_float(m2.y), w3 = __int_as_float(m3.y);
    accx = fmaf(w0 * a0.x, e0.x, accx);
    accy = fmaf(w0 * a0.y, e0.y, accy);
    accx = fmaf(w1 * a1.x, e1.x, accx);
    accy = fmaf(w1 * a1.y, e1.y, accy);
    accx = fmaf(w2 * a2.x, e2.x, accx);
    accy = fmaf(w2 * a2.y, e2.y, accy);
    accx = fmaf(w3 * a3.x, e3.x, accx);
    accy = fmaf(w3 * a3.y, e3.y, accy);
  }
  for (; p < e; ++p) {
    int2 m = emeta[p];
    float2 hv = *(reinterpret_cast<const float2*>(h + (size_t)(m.x & 0xFFFFF) * EMB) + lane);
    float2 ev = *(reinterpret_cast<const float2*>(eb_lds + (m.x >> 20) * EMB) + lane);
    float w = __int_as_float(m.y);
    accx = fmaf(w * hv.x, ev.x, accx);
    accy = fmaf(w * hv.y, ev.y, accy);
  }
  unsigned short hx = f2bf(accx), hy = f2bf(accy);
  unsigned short lx = f2bf(accx - bf2f(hx)), ly = f2bf(accy - bf2f(hy));
  ushort2 hv2; hv2.x = hx; hv2.y = hy;
  ushort2 lv2; lv2.x = lx; lv2.y = ly;
  reinterpret_cast<ushort2*>(Ahi + (size_t)node * EMB)[lane] = hv2;
  reinterpret_cast<ushort2*>(Alo + (size_t)node * EMB)[lane] = lv2;
}

// ---------- h_next = relu(split_bf16(agg) @ W + b) via MFMA ----------
__global__ __launch_bounds__(256) void k_gemm(const unsigned short* __restrict__ Ahi,
    const unsigned short* __restrict__ Alo, const unsigned short* __restrict__ Wt,
    const float* __restrict__ bias, float* __restrict__ outp, int M) {
  int wave = threadIdx.x >> 6, lane = threadIdx.x & 63;
  int lr = lane & 15, lg = lane >> 4;
  int rowbase = blockIdx.x * 128 + wave * 32;
  f32x4 acc[2][8];
#pragma unroll
  for (int m = 0; m < 2; ++m)
#pragma unroll
    for (int n = 0; n < 8; ++n) acc[m][n] = (f32x4){0.f, 0.f, 0.f, 0.f};

#pragma unroll
  for (int kb = 0; kb < 4; ++kb) {
    int koff = kb * 32 + lg * 8;
    bf16x8 ah[2], al[2];
#pragma unroll
    for (int m = 0; m < 2; ++m) {
      int r = rowbase + m * 16 + lr;
      if (r >= M) r = M - 1;                 // clamp; stores are guarded
      ah[m] = *reinterpret_cast<const bf16x8*>(Ahi + (size_t)r * EMB + koff);
      al[m] = *reinterpret_cast<const bf16x8*>(Alo + (size_t)r * EMB + koff);
    }
#pragma unroll
    for (int n = 0; n < 8; ++n) {
      const unsigned short* wp = Wt + (size_t)(n * 16 + lr) * EMB + koff;
      bf16x8 bh = *reinterpret_cast<const bf16x8*>(wp);
      bf16x8 bl = *reinterpret_cast<const bf16x8*>(wp + 128 * EMB);
#pragma unroll
      for (int m = 0; m < 2; ++m) {
        acc[m][n] = __builtin_amdgcn_mfma_f32_16x16x32_bf16(ah[m], bh, acc[m][n], 0, 0, 0);
        acc[m][n] = __builtin_amdgcn_mfma_f32_16x16x32_bf16(al[m], bh, acc[m][n], 0, 0, 0);
        acc[m][n] = __builtin_amdgcn_mfma_f32_16x16x32_bf16(ah[m], bl, acc[m][n], 0, 0, 0);
      }
    }
  }

#pragma unroll
  for (int n = 0; n < 8; ++n) {
    float bv = bias[n * 16 + lr];
#pragma unroll
    for (int m = 0; m < 2; ++m) {
#pragma unroll
      for (int r4 = 0; r4 < 4; ++r4) {
        int row = rowbase + m * 16 + lg * 4 + r4;
        if (row < M)
          outp[(size_t)row * EMB + n * 16 + lr] = fmaxf(acc[m][n][r4] + bv, 0.f);
      }
    }
  }
}

extern "C" void kernel_launch(void* const* d_in, const int* in_sizes, int n_in,
                              void* d_out, int out_size, void* d_ws, size_t ws_size,
                              hipStream_t stream) {
  const int*   x        = (const int*)d_in[0];
  const int*   eidx     = (const int*)d_in[1];
  const int*   eattr    = (const int*)d_in[2];
  const float* atom_emb = (const float*)d_in[3];
  const float* bond_emb = (const float*)d_in[4];
  const float* lin_W    = (const float*)d_in[5];
  const float* lin_b    = (const float*)d_in[6];
  float* out = (float*)d_out;

  const int N = in_sizes[0];
  const int E = in_sizes[1] / 2;
  const int L = in_sizes[5] / (EMB * EMB);
  const int BV = in_sizes[4] / EMB;
  const int* row = eidx;
  const int* col = eidx + E;

  char* ws = (char*)d_ws;
  size_t off = 0;
  auto alloc = [&](size_t bytes) {
    char* p = ws + off;
    off += (bytes + 255) & ~(size_t)255;
    return p;
  };
  float*          hbuf    = (float*)alloc((size_t)N * EMB * 4);
  unsigned short* Ahi     = (unsigned short*)alloc((size_t)N * EMB * 2);
  unsigned short* Alo     = (unsigned short*)alloc((size_t)N * EMB * 2);
  unsigned short* Wt      = (unsigned short*)alloc((size_t)L * 256 * EMB * 2);
  int*            degi8   = (int*)alloc((size_t)N * NC * 4);
  int*            cnt8    = (int*)alloc((size_t)N * NC * 4);
  int*            cnt     = (int*)alloc((size_t)N * 4);
  int*            startp  = (int*)alloc((size_t)(N + 1) * 4);
  float*          dinv    = (float*)alloc((size_t)N * 4);
  int*            partial = (int*)alloc((size_t)1024 * 4);
  int*            ord     = (int*)alloc((size_t)E * 4);
  int2*           emeta   = (int2*)alloc((size_t)E * 8);
  (void)ws_size; (void)n_in; (void)out_size;

  hipMemsetAsync(degi8, 0, (size_t)N * NC * 4, stream);
  hipMemsetAsync(cnt8, 0, (size_t)N * NC * 4, stream);

  int eb = (E + 255) / 256;
  int nb = (N + 255) / 256;
  k_count<<<eb, 256, 0, stream>>>(row, col, degi8, cnt8, ord, E, N);
  k_dinv<<<nb, 256, 0, stream>>>(degi8, dinv, N);
  k_colreduce<<<nb, 256, 0, stream>>>(cnt8, cnt, N);
  k_scan_local<<<nb, 256, 0, stream>>>(cnt, startp, partial, N);
  k_scan_part<<<1, 1024, 0, stream>>>(partial, nb);
  k_scan_add<<<nb, 256, 0, stream>>>(startp, partial, N, E);
  k_fill<<<eb, 256, 0, stream>>>(row, col, eattr, startp, cnt8, ord, dinv, emeta, E, N);
  k_h0<<<((size_t)N * 32 + 255) / 256, 256, 0, stream>>>(x, atom_emb, hbuf, N);
  int wtot = L * EMB * EMB;
  k_wsplit<<<(wtot + 255) / 256, 256, 0, stream>>>(lin_W, Wt, wtot);

  float* hcur = hbuf;
  for (int l = 0; l < L; ++l) {
    k_agg<<<(N + 3) / 4, 256, 0, stream>>>(hcur, startp, emeta, bond_emb, Ahi, Alo, N, BV);
    float* hnext;
    if (l == L - 1) hnext = out;
    else hnext = (hcur == hbuf) ? out : hbuf;
    k_gemm<<<(N + 127) / 128, 256, 0, stream>>>(Ahi, Alo, Wt + (size_t)l * 256 * EMB,
                                                lin_b + (size_t)l * EMB, hnext, N);
    hcur = hnext;
  }
}

// Round 5
// 466.733 us; speedup vs baseline: 1.0100x; 1.0100x over previous
//
#include <hip/hip_runtime.h>

#define EMB 128

typedef __attribute__((ext_vector_type(8))) short bf16x8;
typedef __attribute__((ext_vector_type(4))) float f32x4;

__device__ inline unsigned short f2bf(float f) {
  unsigned u = __float_as_uint(f);
  return (unsigned short)((u + 0x7FFF + ((u >> 16) & 1)) >> 16);   // RNE
}
__device__ inline float bf2f(unsigned short s) {
  return __uint_as_float(((unsigned)s) << 16);
}

// ---------- CSR build: compact histograms (atomics are memory-side; small
// footprint is fastest — r2/r3/r4 A/B showed padding/privatization hurt) ----
__global__ __launch_bounds__(256) void k_count(const int* __restrict__ row,
    const int* __restrict__ col, int* __restrict__ degi,
    int* __restrict__ cnt, int* __restrict__ ord, int E) {
  int k = blockIdx.x * 256 + threadIdx.x;
  if (k < E) {
    atomicAdd(&degi[row[k]], 1);              // out-degree (GCN norm)
    ord[k] = atomicAdd(&cnt[col[k]], 1);      // in-degree + arrival order
  }
}

__global__ __launch_bounds__(256) void k_dinv(const int* __restrict__ degi,
                                              float* __restrict__ dinv, int N) {
  int i = blockIdx.x * 256 + threadIdx.x;
  if (i < N) {
    int d = degi[i];
    float df = (float)(d == 0 ? 1 : d);
    dinv[i] = 1.0f / sqrtf(df);
  }
}

// ---------- multi-block exclusive scan ----------
__global__ __launch_bounds__(256) void k_scan_local(const int* __restrict__ cnt,
    int* __restrict__ startp, int* __restrict__ partial, int N) {
  __shared__ int lds[256];
  int tid = threadIdx.x;
  int i = blockIdx.x * 256 + tid;
  int v = (i < N) ? cnt[i] : 0;
  lds[tid] = v;
  __syncthreads();
#pragma unroll
  for (int off = 1; off < 256; off <<= 1) {
    int t = (tid >= off) ? lds[tid - off] : 0;
    __syncthreads();
    lds[tid] += t;
    __syncthreads();
  }
  if (i < N) startp[i] = lds[tid] - v;
  if (tid == 255) partial[blockIdx.x] = lds[255];
}

__global__ void k_scan_part(int* __restrict__ partial, int nb) {
  __shared__ int lds[1024];
  int tid = threadIdx.x;
  int v = (tid < nb) ? partial[tid] : 0;
  lds[tid] = v;
  __syncthreads();
  for (int off = 1; off < 1024; off <<= 1) {
    int t = (tid >= off) ? lds[tid - off] : 0;
    __syncthreads();
    lds[tid] += t;
    __syncthreads();
  }
  if (tid < nb) partial[tid] = lds[tid] - v;
}

__global__ __launch_bounds__(256) void k_scan_add(int* __restrict__ startp,
    const int* __restrict__ partial, int N, int E) {
  int i = blockIdx.x * 256 + threadIdx.x;
  if (i < N) startp[i] += partial[blockIdx.x];
  if (i == 0) startp[N] = E;
}

__global__ __launch_bounds__(256) void k_fill(const int* __restrict__ row,
    const int* __restrict__ col, const int* __restrict__ attr,
    const int* __restrict__ startp, const int* __restrict__ ord,
    const float* __restrict__ dinv, int2* __restrict__ emeta, int E) {
  int k = blockIdx.x * 256 + threadIdx.x;
  if (k < E) {
    int r = row[k], c = col[k];
    int pos = startp[c] + ord[k];
    int2 m;
    m.x = r | (attr[k] << 20);
    m.y = __float_as_int(dinv[r] * dinv[c]);
    emeta[pos] = m;
  }
}

// ---------- h0 = atom_emb[x] ----------
__global__ __launch_bounds__(256) void k_h0(const int* __restrict__ x,
    const float* __restrict__ atom_emb, float* __restrict__ h, int N) {
  int t = blockIdx.x * 256 + threadIdx.x;
  int i = t >> 5, f = t & 31;
  if (i < N) {
    float4 v = reinterpret_cast<const float4*>(atom_emb)[x[i] * 32 + f];
    reinterpret_cast<float4*>(h)[i * 32 + f] = v;
  }
}

// ---------- W split: Wt[l][ 0..127 ][k]=hi, Wt[l][128..255][k]=lo (col-major) ----
__global__ __launch_bounds__(256) void k_wsplit(const float* __restrict__ W,
    unsigned short* __restrict__ Wt, int total) {
  int t = blockIdx.x * 256 + threadIdx.x;   // t = (l*128 + k)*128 + n
  if (t >= total) return;
  int n = t & 127, k = (t >> 7) & 127, l = t >> 14;
  float v = W[t];
  unsigned short hi = f2bf(v);
  unsigned short lo = f2bf(v - bf2f(hi));
  size_t base = (size_t)l * 256 * EMB;
  Wt[base + (size_t)n * EMB + k] = hi;
  Wt[base + (size_t)(128 + n) * EMB + k] = lo;
}

// ---------- aggregation: one wave per node, 2 edges per gather instr ----------
// half-wave (32 lanes x float4 = 512B) covers a full h row; lanes 0-31 take
// even edges, 32-63 odd. 4 pair-steps in flight. Epilogue: shfl_xor(32) reduce.
#define UN 4
__global__ __launch_bounds__(256) void k_agg(const float* __restrict__ h,
    const int* __restrict__ startp, const int2* __restrict__ emeta,
    const float* __restrict__ bond_emb, unsigned short* __restrict__ Ahi,
    unsigned short* __restrict__ Alo, int N, int BV) {
  __shared__ float eb_lds[16 * EMB];           // bond table, 8 KB
  for (int t = threadIdx.x; t < BV * (EMB / 4); t += 256)
    reinterpret_cast<float4*>(eb_lds)[t] =
        reinterpret_cast<const float4*>(bond_emb)[t];
  __syncthreads();

  int wave = threadIdx.x >> 6, lane = threadIdx.x & 63;
  int half = lane >> 5, sl = lane & 31;
  int node = blockIdx.x * 4 + wave;
  if (node >= N) return;
  int s = startp[node], e = startp[node + 1];
  float4 acc = make_float4(0.f, 0.f, 0.f, 0.f);
  int npair = (e - s + 1) >> 1;

  for (int step = 0; step < npair; step += UN) {
    int2 m[UN];
#pragma unroll
    for (int u = 0; u < UN; ++u) {
      int ep = s + 2 * (step + u) + half;
      // invalid slots: meta = {0,0} -> w = +0.0f, src = 0, bond = 0 -> adds 0
      m[u] = (ep < e) ? emeta[ep] : make_int2(0, 0);
    }
    float4 hv[UN];
#pragma unroll
    for (int u = 0; u < UN; ++u)
      hv[u] = *(reinterpret_cast<const float4*>(h + (size_t)(m[u].x & 0xFFFFF) * EMB) + sl);
#pragma unroll
    for (int u = 0; u < UN; ++u) {
      float w = __int_as_float(m[u].y);
      float4 ev = *(reinterpret_cast<const float4*>(eb_lds + (m[u].x >> 20) * EMB) + sl);
      acc.x = fmaf(w * hv[u].x, ev.x, acc.x);
      acc.y = fmaf(w * hv[u].y, ev.y, acc.y);
      acc.z = fmaf(w * hv[u].z, ev.z, acc.z);
      acc.w = fmaf(w * hv[u].w, ev.w, acc.w);
    }
  }

  // combine the two halves: lane l and l^32 hold the same 4 elements
  acc.x += __shfl_xor(acc.x, 32);
  acc.y += __shfl_xor(acc.y, 32);
  acc.z += __shfl_xor(acc.z, 32);
  acc.w += __shfl_xor(acc.w, 32);

  if (half == 0) {
    unsigned short h0 = f2bf(acc.x), h1 = f2bf(acc.y);
    unsigned short h2 = f2bf(acc.z), h3 = f2bf(acc.w);
    ushort4 hi4; hi4.x = h0; hi4.y = h1; hi4.z = h2; hi4.w = h3;
    ushort4 lo4;
    lo4.x = f2bf(acc.x - bf2f(h0));
    lo4.y = f2bf(acc.y - bf2f(h1));
    lo4.z = f2bf(acc.z - bf2f(h2));
    lo4.w = f2bf(acc.w - bf2f(h3));
    *(reinterpret_cast<ushort4*>(Ahi + (size_t)node * EMB) + sl) = hi4;
    *(reinterpret_cast<ushort4*>(Alo + (size_t)node * EMB) + sl) = lo4;
  }
}

// ---------- h_next = relu(split_bf16(agg) @ W + b) via MFMA ----------
__global__ __launch_bounds__(256) void k_gemm(const unsigned short* __restrict__ Ahi,
    const unsigned short* __restrict__ Alo, const unsigned short* __restrict__ Wt,
    const float* __restrict__ bias, float* __restrict__ outp, int M) {
  int wave = threadIdx.x >> 6, lane = threadIdx.x & 63;
  int lr = lane & 15, lg = lane >> 4;
  int rowbase = blockIdx.x * 128 + wave * 32;
  f32x4 acc[2][8];
#pragma unroll
  for (int m = 0; m < 2; ++m)
#pragma unroll
    for (int n = 0; n < 8; ++n) acc[m][n] = (f32x4){0.f, 0.f, 0.f, 0.f};

#pragma unroll
  for (int kb = 0; kb < 4; ++kb) {
    int koff = kb * 32 + lg * 8;
    bf16x8 ah[2], al[2];
#pragma unroll
    for (int m = 0; m < 2; ++m) {
      int r = rowbase + m * 16 + lr;
      if (r >= M) r = M - 1;                 // clamp; stores are guarded
      ah[m] = *reinterpret_cast<const bf16x8*>(Ahi + (size_t)r * EMB + koff);
      al[m] = *reinterpret_cast<const bf16x8*>(Alo + (size_t)r * EMB + koff);
    }
#pragma unroll
    for (int n = 0; n < 8; ++n) {
      const unsigned short* wp = Wt + (size_t)(n * 16 + lr) * EMB + koff;
      bf16x8 bh = *reinterpret_cast<const bf16x8*>(wp);
      bf16x8 bl = *reinterpret_cast<const bf16x8*>(wp + 128 * EMB);
#pragma unroll
      for (int m = 0; m < 2; ++m) {
        acc[m][n] = __builtin_amdgcn_mfma_f32_16x16x32_bf16(ah[m], bh, acc[m][n], 0, 0, 0);
        acc[m][n] = __builtin_amdgcn_mfma_f32_16x16x32_bf16(al[m], bh, acc[m][n], 0, 0, 0);
        acc[m][n] = __builtin_amdgcn_mfma_f32_16x16x32_bf16(ah[m], bl, acc[m][n], 0, 0, 0);
      }
    }
  }

#pragma unroll
  for (int n = 0; n < 8; ++n) {
    float bv = bias[n * 16 + lr];
#pragma unroll
    for (int m = 0; m < 2; ++m) {
#pragma unroll
      for (int r4 = 0; r4 < 4; ++r4) {
        int row = rowbase + m * 16 + lg * 4 + r4;
        if (row < M)
          outp[(size_t)row * EMB + n * 16 + lr] = fmaxf(acc[m][n][r4] + bv, 0.f);
      }
    }
  }
}

extern "C" void kernel_launch(void* const* d_in, const int* in_sizes, int n_in,
                              void* d_out, int out_size, void* d_ws, size_t ws_size,
                              hipStream_t stream) {
  const int*   x        = (const int*)d_in[0];
  const int*   eidx     = (const int*)d_in[1];
  const int*   eattr    = (const int*)d_in[2];
  const float* atom_emb = (const float*)d_in[3];
  const float* bond_emb = (const float*)d_in[4];
  const float* lin_W    = (const float*)d_in[5];
  const float* lin_b    = (const float*)d_in[6];
  float* out = (float*)d_out;

  const int N = in_sizes[0];
  const int E = in_sizes[1] / 2;
  const int L = in_sizes[5] / (EMB * EMB);
  const int BV = in_sizes[4] / EMB;
  const int* row = eidx;
  const int* col = eidx + E;

  char* ws = (char*)d_ws;
  size_t off = 0;
  auto alloc = [&](size_t bytes) {
    char* p = ws + off;
    off += (bytes + 255) & ~(size_t)255;
    return p;
  };
  float*          hbuf    = (float*)alloc((size_t)N * EMB * 4);
  unsigned short* Ahi     = (unsigned short*)alloc((size_t)N * EMB * 2);
  unsigned short* Alo     = (unsigned short*)alloc((size_t)N * EMB * 2);
  unsigned short* Wt      = (unsigned short*)alloc((size_t)L * 256 * EMB * 2);
  int*            degi    = (int*)alloc((size_t)N * 4);
  int*            cnt     = (int*)alloc((size_t)N * 4);
  int*            startp  = (int*)alloc((size_t)(N + 1) * 4);
  float*          dinv    = (float*)alloc((size_t)N * 4);
  int*            partial = (int*)alloc((size_t)1024 * 4);
  int*            ord     = (int*)alloc((size_t)E * 4);
  int2*           emeta   = (int2*)alloc((size_t)E * 8);
  (void)ws_size; (void)n_in; (void)out_size;

  hipMemsetAsync(degi, 0, (size_t)N * 4, stream);
  hipMemsetAsync(cnt, 0, (size_t)N * 4, stream);

  int eb = (E + 255) / 256;
  int nb = (N + 255) / 256;
  k_count<<<eb, 256, 0, stream>>>(row, col, degi, cnt, ord, E);
  k_dinv<<<nb, 256, 0, stream>>>(degi, dinv, N);
  k_scan_local<<<nb, 256, 0, stream>>>(cnt, startp, partial, N);
  k_scan_part<<<1, 1024, 0, stream>>>(partial, nb);
  k_scan_add<<<nb, 256, 0, stream>>>(startp, partial, N, E);
  k_fill<<<eb, 256, 0, stream>>>(row, col, eattr, startp, ord, dinv, emeta, E);
  k_h0<<<((size_t)N * 32 + 255) / 256, 256, 0, stream>>>(x, atom_emb, hbuf, N);
  int wtot = L * EMB * EMB;
  k_wsplit<<<(wtot + 255) / 256, 256, 0, stream>>>(lin_W, Wt, wtot);

  float* hcur = hbuf;
  for (int l = 0; l < L; ++l) {
    k_agg<<<(N + 3) / 4, 256, 0, stream>>>(hcur, startp, emeta, bond_emb, Ahi, Alo, N, BV);
    float* hnext;
    if (l == L - 1) hnext = out;
    else hnext = (hcur == hbuf) ? out : hbuf;
    k_gemm<<<(N + 127) / 128, 256, 0, stream>>>(Ahi, Alo, Wt + (size_t)l * 256 * EMB,
                                                lin_b + (size_t)l * EMB, hnext, N);
    hcur = hnext;
  }
}